// Round 11
// baseline (2641.615 us; speedup 1.0000x reference)
//
#include <hip/hip_runtime.h>

// LSTM B=64 T=512 I=512 H=1024 — round 18.
// R17 (single-plane h): 2326us, absmax unmoved at bf16 floor => accuracy
// margin confirmed. Schedule is locked (R14-R16 all regressed). Remaining gap
// vs modeled chain (~4.5 vs ~3us) = contention inflation of coherent ops =>
// keep cutting coherent TRANSACTION COUNT.
// R18: widen the h publish. Old: 65K separate u16 sc0sc1 stores/step (256
// blocks x 2 kh0 waves x 64 lanes x 2) — each a partial-dword write-through
// (RMW at the LLC slice). New: each kh0 wave bounces its 128 h values
// through a 512B wave-local LDS buffer (swb[mt][bsub][4u+q], same-wave,
// compiler-managed lgkmcnt, no barrier), then lanes 0-15 issue ONE
// global_store_dwordx4 sc0 sc1 each (the wave's region is 256B contiguous).
// 65K -> 8K store transactions, identical bytes/layout, publish/drain/atomic
// timing and the R13/R17 protocol byte-identical. Micro: gate red reads
// vectorized to float4 (24 scalar -> 6 b128 LDS reads).
// Predicted: 2326 -> ~2100-2250us; absmax unchanged. If neutral: TA was
// already coalescing -> next attack post-barrier compute.

typedef short bf16x8 __attribute__((ext_vector_type(8)));
typedef float f32x4  __attribute__((ext_vector_type(4)));
typedef unsigned u32x4 __attribute__((ext_vector_type(4)));

#define BB 64
#define TT 512
#define II 512
#define HH 1024

#define NBLK 256
#define NTHR 512

// ws layout (bytes)
#define WS_CNT_OFF   0                       // 16 counters, 256B apart (memset 8K)
#define WS_HPAKH_OFF 8192                    // u16 [2][HH/8][BB][8] = 256 KB
#define WS_XPAKH_OFF (1 << 20)               // u16 [TT][II/8][BB][8] = 32 MB
#define WS_XPAKL_OFF ((1 << 20) + (32u << 20))

#define HBUF_STRIDE 65536                    // u16 per h buffer
#define XT_STRIDE   32768                    // u16 per timestep of x

__device__ __forceinline__ int atomic_add_rlx(int* p) {
    return __hip_atomic_fetch_add(p, 1, __ATOMIC_RELAXED, __HIP_MEMORY_SCOPE_AGENT);
}
__device__ __forceinline__ int load_rlx(const int* p) {
    return __hip_atomic_load(p, __ATOMIC_RELAXED, __HIP_MEMORY_SCOPE_AGENT);
}

__device__ __forceinline__ float fast_sigmoid(float x) {
    return 1.0f / (1.0f + __expf(-x));
}
__device__ __forceinline__ float fast_tanh(float x) {
    x = fminf(15.0f, fmaxf(-15.0f, x));
    const float e = __expf(2.0f * x);
    return (e - 1.0f) / (e + 1.0f);
}

// fp32 -> bf16 hi + bf16 lo-of-residual (RNE both)
__device__ __forceinline__ void split_bf16(float x, unsigned& hi, unsigned& lo)
{
    unsigned b = __float_as_uint(x);
    hi = (b + 0x7fffu + ((b >> 16) & 1u)) >> 16;
    float r = x - __uint_as_float(hi << 16);
    unsigned bl = __float_as_uint(r);
    lo = (bl + 0x7fffu + ((bl >> 16) & 1u)) >> 16;
}
// fp32 -> bf16 (RNE), hi only
__device__ __forceinline__ unsigned short bf16_rne(float x)
{
    unsigned b = __float_as_uint(x);
    return (unsigned short)((b + 0x7fffu + ((b >> 16) & 1u)) >> 16);
}

#define MFMA(A, B, C) __builtin_amdgcn_mfma_f32_16x16x32_bf16((A), (B), (C), 0, 0, 0)

// coherent 16B load, issued WITHOUT wait (MUST pair with WAITSTG4 below)
__device__ __forceinline__ void issue_coh(const unsigned short* p, u32x4& d)
{
    asm volatile("global_load_dwordx4 %0, %1, off sc0 sc1" : "=v"(d) : "v"(p));
}
// coherent 16B store (write-through to LLC, matches load side)
__device__ __forceinline__ void store_coh16(unsigned short* p, u32x4 v)
{
    asm volatile("global_store_dwordx4 %0, %1, off sc0 sc1" :: "v"(p), "v"(v)
                 : "memory");
}
// drain all VMEM; loaded values flow THROUGH the wait so uses can't be hoisted
#define WAITSTG4(FH)                                                          \
    asm volatile("s_waitcnt vmcnt(0)"                                         \
        : "+v"(FH[0]), "+v"(FH[1]), "+v"(FH[2]), "+v"(FH[3])                  \
        :: "memory")

// x -> split planes, layout [t][k>>3][b][k&7] u16 per plane
__global__ void __launch_bounds__(256)
transpose_pack_x(const float* __restrict__ x,
                 unsigned short* __restrict__ xH, unsigned short* __restrict__ xL)
{
    __shared__ float tile[64][65];
    const int t   = (int)blockIdx.x;
    const int tid = (int)threadIdx.x;
    const int li  = tid & 63;
    const int w4  = tid >> 6;

    for (int kc = 0; kc < II; kc += 64) {
#pragma unroll
        for (int r = 0; r < 16; ++r) {
            const int b = w4 * 16 + r;
            tile[b][li] = x[((size_t)b * TT + t) * II + kc + li];
        }
        __syncthreads();
#pragma unroll
        for (int half = 0; half < 2; ++half) {
            const int u  = tid + half * 256;      // u = k8*64 + b
            const int k8 = u >> 6, b = u & 63;
            unsigned short oh[8], ol[8];
#pragma unroll
            for (int e = 0; e < 8; ++e) {
                unsigned hi, lo;
                split_bf16(tile[b][k8 * 8 + e], hi, lo);
                oh[e] = (unsigned short)hi;
                ol[e] = (unsigned short)lo;
            }
            const size_t idx = (size_t)t * XT_STRIDE + ((kc >> 3) + k8) * 512 + b * 8;
            *(uint4*)(xH + idx) = *(const uint4*)oh;
            *(uint4*)(xL + idx) = *(const uint4*)ol;
        }
        __syncthreads();
    }
}

__global__ void __launch_bounds__(NTHR, 2)
lstm_mfma(const unsigned short* __restrict__ xH,
          const unsigned short* __restrict__ xL,
          const int*   __restrict__ lens,
          const float* __restrict__ Wih,     // [4H][I]
          const float* __restrict__ Whh,     // [4H][H]
          const float* __restrict__ bih,
          const float* __restrict__ bhh,
          unsigned short* __restrict__ hH,   // [2][H/8][B][8] bf16 only
          int*   __restrict__ cnts,          // 16 counters, 64-int stride
          float* __restrict__ out)           // [B][H]
{
    __shared__ float red[2][2][3][2][16][17];     // [pa][mt][kh-1][u][bsub][17] ~26KB
    __shared__ unsigned short hstg[128][128];     // [chunk][b16*8] 32KB
    __shared__ unsigned short swb[2][16][8];      // [mt][bsub][j] store bounce 512B
    __shared__ float biaslds[4][16];              // [gate][j-within-block]
    __shared__ int hflag;                         // step-ready broadcast

    const int tid  = (int)threadIdx.x;
    const int l    = tid & 63;
    const int p    = __builtin_amdgcn_readfirstlane(tid >> 6);  // wave 0..7
    const int kh   = p & 3;                  // k-split 0..3
    const int mt   = p >> 2;                 // m-pair 0..1 (tiles mt*2+u)
    const int bsub = l & 15;
    const int q    = l >> 4;                 // quad

    const int jt = (int)blockIdx.x >> 2;     // 0..63  (16 channels each)
    const int bq = (int)blockIdx.x & 3;      // 0..3   (16 batch each)
    const int j0 = jt * 16;
    const int b0 = bq * 16;

    const int bofs = (b0 + bsub) * 8;        // u16 offset of my batch lane

    int*       prodc = cnts + (bq * 4 + (jt >> 4)) * 64;  // my quarter's counter
    const int* pollc = cnts + (bq * 4 + (l & 3)) * 64;    // poller: lane l&3's quarter

    // ---- weight A-fragments -> registers (persist across all t) ----
    bf16x8 whi[2][12], wlo[2][12];
#pragma unroll
    for (int u = 0; u < 2; ++u) {
        const int row = (l & 3) * HH + j0 + (mt * 2 + u) * 4 + ((l & 15) >> 2);
#pragma unroll
        for (int kt = 0; kt < 12; ++kt) {
            const int ktg = (kt < 4) ? (4 * kh + kt) : (16 + 8 * kh + (kt - 4));
            const float* src = (ktg < 16)
                ? (Wih + (size_t)row * II + ktg * 32 + q * 8)
                : (Whh + (size_t)row * HH + (ktg - 16) * 32 + q * 8);
            const float4 w0 = *(const float4*)src;
            const float4 w1 = *(const float4*)(src + 4);
            const float wf[8] = {w0.x, w0.y, w0.z, w0.w, w1.x, w1.y, w1.z, w1.w};
#pragma unroll
            for (int e = 0; e < 8; ++e) {
                unsigned hi, lo;
                split_bf16(wf[e], hi, lo);
                whi[u][kt][e] = (short)hi;
                wlo[u][kt][e] = (short)lo;
            }
        }
    }

    // ---- per-cell state; init h_0, ack, publish (R13 protocol) ----
    float c[2] = {0.f, 0.f}, lasth[2] = {0.f, 0.f};
    int len = 0;
    const size_t hchunk = (size_t)(2 * jt + mt) * 512;  // my output chunk row

    if (kh == 0) {
        len = lens[b0 + bsub];
        if (l < 16)                          // one 16B zero store per bsub slice
            store_coh16(hH + hchunk + (b0 + l) * 8, (u32x4){0u, 0u, 0u, 0u});
        asm volatile("s_waitcnt vmcnt(0)" ::: "memory");
        if (l == 0) atomic_add_rlx(prodc);               // -> 32 when all ready
    }

    // ---- bias table + flag init before any poll ----
    if (tid < 64) {
        const int gi = tid >> 4, jj = tid & 15;
        biaslds[gi][jj] = bih[gi * HH + j0 + jj] + bhh[gi * HH + j0 + jj];
    }
    if (tid == 0)
        __hip_atomic_store(&hflag, 0, __ATOMIC_RELAXED, __HIP_MEMORY_SCOPE_WORKGROUP);
    __syncthreads();

    for (int t = 0; t < TT; ++t) {
        // ---- x-part (plain cached b128 loads; independent of h_t) ----
        f32x4 s0[2], s12[2];
#pragma unroll
        for (int u = 0; u < 2; ++u)
            s0[u] = s12[u] = (f32x4){0.f, 0.f, 0.f, 0.f};
        {
            const unsigned short* xh = xH + (size_t)t * XT_STRIDE;
            const unsigned short* xl = xL + (size_t)t * XT_STRIDE;
#pragma unroll
            for (int xi = 0; xi < 4; ++xi) {
                const int idx = ((4 * kh + xi) * 4 + q) * 512 + bofs;
                const bf16x8 ahi = *(const bf16x8*)(xh + idx);
                const bf16x8 alo = *(const bf16x8*)(xl + idx);
#pragma unroll
                for (int u = 0; u < 2; ++u) {
                    s0[u]  = MFMA(whi[u][xi], ahi, s0[u]);
                    s12[u] = MFMA(whi[u][xi], alo, s12[u]);
                    s12[u] = MFMA(wlo[u][xi], ahi, s12[u]);
                }
            }
        }

        // ---- step-ready: wave 7 polls 4 quarter counters, others spin LDS ----
        {
            const int need = 32 * (t + 1);
            if (p == 7) {
                while (load_rlx(pollc) < need)       // divergent: exits when all
                    __builtin_amdgcn_s_sleep(1);     // 4 quarters (l&3) pass
                if (l == 0)
                    __hip_atomic_store(&hflag, t + 1, __ATOMIC_RELAXED,
                                       __HIP_MEMORY_SCOPE_WORKGROUP);
            } else {
                while (__hip_atomic_load(&hflag, __ATOMIC_RELAXED,
                                         __HIP_MEMORY_SCOPE_WORKGROUP) < t + 1)
                    __builtin_amdgcn_s_sleep(1);
            }
            asm volatile("" ::: "memory");
        }

        // ---- h-part stage: each wave coherently loads its 16 chunks ----
        const unsigned short* hph = hH + (t & 1) * HBUF_STRIDE;
        {
            u32x4 fh[4];
#pragma unroll
            for (int r = 0; r < 4; ++r) {
                const int chunk = kh * 32 + mt * 16 + r * 4 + q;
                issue_coh(hph + chunk * 512 + bofs, fh[r]);
            }
            WAITSTG4(fh);
#pragma unroll
            for (int r = 0; r < 4; ++r) {
                const int chunk = kh * 32 + mt * 16 + r * 4 + q;
                *(u32x4*)&hstg[chunk][bsub * 8] = fh[r];
            }
        }
        __syncthreads();

        // ---- h-part consume: 8 k-steps of my quarter from LDS (2 streams) ----
#pragma unroll
        for (int hi2 = 0; hi2 < 8; ++hi2) {
            const int chunk = kh * 32 + hi2 * 4 + q;
            const bf16x8 ahi = *(const bf16x8*)&hstg[chunk][bsub * 8];
#pragma unroll
            for (int u = 0; u < 2; ++u) {
                s0[u]  = MFMA(whi[u][4 + hi2], ahi, s0[u]);
                s12[u] = MFMA(wlo[u][4 + hi2], ahi, s12[u]);
            }
        }

        // ---- merge streams + single-phase cross-wave reduction ----
        f32x4 acc[2];
#pragma unroll
        for (int u = 0; u < 2; ++u) acc[u] = s0[u] + s12[u];
        const int pa = t & 1;

        if (kh != 0) {
#pragma unroll
            for (int u = 0; u < 2; ++u)
#pragma unroll
                for (int i = 0; i < 4; ++i)
                    red[pa][mt][kh - 1][u][bsub][4 * q + i] = acc[u][i];
        }
        __syncthreads();

        // ---- gate math (kh==0), wide h store, drain, publish ----
        if (kh == 0) {
            unsigned short* dsth = hH + ((t + 1) & 1) * HBUF_STRIDE + hchunk;
#pragma unroll
            for (int u = 0; u < 2; ++u) {
                const int jj = (mt * 2 + u) * 4 + q;
                const f32x4 r0 = *(const f32x4*)&red[pa][mt][0][u][bsub][4 * q];
                const f32x4 r1 = *(const f32x4*)&red[pa][mt][1][u][bsub][4 * q];
                const f32x4 r2 = *(const f32x4*)&red[pa][mt][2][u][bsub][4 * q];
                float g4[4];
#pragma unroll
                for (int i = 0; i < 4; ++i)
                    g4[i] = acc[u][i] + biaslds[i][jj] + r0[i] + r1[i] + r2[i];
                const float ig = fast_sigmoid(g4[0]);
                const float fg = fast_sigmoid(g4[1]);
                const float gg = fast_tanh(g4[2]);
                const float og = fast_sigmoid(g4[3]);
                c[u] = fg * c[u] + ig * gg;
                const float h = og * fast_tanh(c[u]);
                swb[mt][bsub][4 * u + q] = bf16_rne(h);   // wave-local bounce
                if (t == len - 1) lasth[u] = h;
            }
            // lanes 0-15: one coherent 16B store each (256B/wave contiguous)
            if (l < 16)
                store_coh16(dsth + (b0 + l) * 8, *(const u32x4*)&swb[mt][l][0]);
            asm volatile("s_waitcnt vmcnt(0)" ::: "memory");  // h stores visible
            if (l == 0) atomic_add_rlx(prodc);                // publish h_{t+1}
        }
    }

    // ---- epilogue ----
    if (kh == 0) {
#pragma unroll
        for (int u = 0; u < 2; ++u) {
            const int jj = (mt * 2 + u) * 4 + q;
            out[(size_t)(b0 + bsub) * HH + j0 + jj] = lasth[u];
        }
    }
}

extern "C" void kernel_launch(void* const* d_in, const int* in_sizes, int n_in,
                              void* d_out, int out_size, void* d_ws, size_t ws_size,
                              hipStream_t stream)
{
    const float* seq  = (const float*)d_in[0];
    const int*   lens = (const int*)  d_in[1];
    const float* Wih  = (const float*)d_in[2];
    const float* Whh  = (const float*)d_in[3];
    const float* bih  = (const float*)d_in[4];
    const float* bhh  = (const float*)d_in[5];
    float* out = (float*)d_out;

    char* ws = (char*)d_ws;
    int*            cnts = (int*)           (ws + WS_CNT_OFF);
    unsigned short* hH   = (unsigned short*)(ws + WS_HPAKH_OFF);
    unsigned short* xH   = (unsigned short*)(ws + WS_XPAKH_OFF);
    unsigned short* xL   = (unsigned short*)(ws + WS_XPAKL_OFF);

    hipMemsetAsync(cnts, 0, 8192, stream);   // monotonic counters start at 0
    transpose_pack_x<<<dim3(TT), dim3(256), 0, stream>>>(seq, xH, xL);
    lstm_mfma<<<dim3(NBLK), dim3(NTHR), 0, stream>>>(xH, xL, lens, Wih, Whh, bih, bhh,
                                                     hH, cnts, out);
}

// Round 12
// 2307.940 us; speedup vs baseline: 1.1446x; 1.1446x over previous
//
#include <hip/hip_runtime.h>

// LSTM B=64 T=512 I=512 H=1024 — round 19.
// R18 post-mortem (+13.5%): TA already coalesced the contiguous u16 h-stores
// (WRITE_SIZE even fell); the LDS bounce + 16-lane store added ~0.6us/step to
// the kh0 publish chain. Rule locked: never add hops to the publish path.
// REVERT to R17 (2326us).
// R19 change: replace post-stage __syncthreads (sync#1) with a PAIR BARRIER.
// Sync#1 only existed so the mt-pair could exchange staged halves, but it
// stalls all 8 waves on the slowest stage burst. Now: after stage ds_writes,
// each wave RELEASE-stores t+1 to pairbar[kh][mt] (lgkmcnt drained by the
// release), then ACQUIRE-spins on pairbar[kh][mt^1]. Pairs proceed
// independently; block reconvergence deferred to sync#2.
// Safety: (i) consume reads only self+pair chunks => pair handshake gives
// visibility (per-wave LDS in-order + release/acquire); (ii) stage(t+1)
// overwrite still fenced by sync#2 (reaching stage(t+1) => passed sync#2 =>
// pair finished consume(t)); (iii) publish/poll protocol byte-identical R17.

typedef short bf16x8 __attribute__((ext_vector_type(8)));
typedef float f32x4  __attribute__((ext_vector_type(4)));
typedef unsigned u32x4 __attribute__((ext_vector_type(4)));

#define BB 64
#define TT 512
#define II 512
#define HH 1024

#define NBLK 256
#define NTHR 512

// ws layout (bytes)
#define WS_CNT_OFF   0                       // 16 counters, 256B apart (memset 8K)
#define WS_HPAKH_OFF 8192                    // u16 [2][HH/8][BB][8] = 256 KB
#define WS_XPAKH_OFF (1 << 20)               // u16 [TT][II/8][BB][8] = 32 MB
#define WS_XPAKL_OFF ((1 << 20) + (32u << 20))

#define HBUF_STRIDE 65536                    // u16 per h buffer
#define XT_STRIDE   32768                    // u16 per timestep of x

__device__ __forceinline__ int atomic_add_rlx(int* p) {
    return __hip_atomic_fetch_add(p, 1, __ATOMIC_RELAXED, __HIP_MEMORY_SCOPE_AGENT);
}
__device__ __forceinline__ int load_rlx(const int* p) {
    return __hip_atomic_load(p, __ATOMIC_RELAXED, __HIP_MEMORY_SCOPE_AGENT);
}
__device__ __forceinline__ void store_wt_u16(unsigned short* p, unsigned short v) {
    __hip_atomic_store(p, v, __ATOMIC_RELAXED, __HIP_MEMORY_SCOPE_AGENT);
}

__device__ __forceinline__ float fast_sigmoid(float x) {
    return 1.0f / (1.0f + __expf(-x));
}
__device__ __forceinline__ float fast_tanh(float x) {
    x = fminf(15.0f, fmaxf(-15.0f, x));
    const float e = __expf(2.0f * x);
    return (e - 1.0f) / (e + 1.0f);
}

// fp32 -> bf16 hi + bf16 lo-of-residual (RNE both)
__device__ __forceinline__ void split_bf16(float x, unsigned& hi, unsigned& lo)
{
    unsigned b = __float_as_uint(x);
    hi = (b + 0x7fffu + ((b >> 16) & 1u)) >> 16;
    float r = x - __uint_as_float(hi << 16);
    unsigned bl = __float_as_uint(r);
    lo = (bl + 0x7fffu + ((bl >> 16) & 1u)) >> 16;
}
// fp32 -> bf16 (RNE), hi only
__device__ __forceinline__ unsigned short bf16_rne(float x)
{
    unsigned b = __float_as_uint(x);
    return (unsigned short)((b + 0x7fffu + ((b >> 16) & 1u)) >> 16);
}

#define MFMA(A, B, C) __builtin_amdgcn_mfma_f32_16x16x32_bf16((A), (B), (C), 0, 0, 0)

// coherent 16B load, issued WITHOUT wait (MUST pair with WAITSTG4 below)
__device__ __forceinline__ void issue_coh(const unsigned short* p, u32x4& d)
{
    asm volatile("global_load_dwordx4 %0, %1, off sc0 sc1" : "=v"(d) : "v"(p));
}
// drain all VMEM; loaded values flow THROUGH the wait so uses can't be hoisted
#define WAITSTG4(FH)                                                          \
    asm volatile("s_waitcnt vmcnt(0)"                                         \
        : "+v"(FH[0]), "+v"(FH[1]), "+v"(FH[2]), "+v"(FH[3])                  \
        :: "memory")

// x -> split planes, layout [t][k>>3][b][k&7] u16 per plane
__global__ void __launch_bounds__(256)
transpose_pack_x(const float* __restrict__ x,
                 unsigned short* __restrict__ xH, unsigned short* __restrict__ xL)
{
    __shared__ float tile[64][65];
    const int t   = (int)blockIdx.x;
    const int tid = (int)threadIdx.x;
    const int li  = tid & 63;
    const int w4  = tid >> 6;

    for (int kc = 0; kc < II; kc += 64) {
#pragma unroll
        for (int r = 0; r < 16; ++r) {
            const int b = w4 * 16 + r;
            tile[b][li] = x[((size_t)b * TT + t) * II + kc + li];
        }
        __syncthreads();
#pragma unroll
        for (int half = 0; half < 2; ++half) {
            const int u  = tid + half * 256;      // u = k8*64 + b
            const int k8 = u >> 6, b = u & 63;
            unsigned short oh[8], ol[8];
#pragma unroll
            for (int e = 0; e < 8; ++e) {
                unsigned hi, lo;
                split_bf16(tile[b][k8 * 8 + e], hi, lo);
                oh[e] = (unsigned short)hi;
                ol[e] = (unsigned short)lo;
            }
            const size_t idx = (size_t)t * XT_STRIDE + ((kc >> 3) + k8) * 512 + b * 8;
            *(uint4*)(xH + idx) = *(const uint4*)oh;
            *(uint4*)(xL + idx) = *(const uint4*)ol;
        }
        __syncthreads();
    }
}

__global__ void __launch_bounds__(NTHR, 2)
lstm_mfma(const unsigned short* __restrict__ xH,
          const unsigned short* __restrict__ xL,
          const int*   __restrict__ lens,
          const float* __restrict__ Wih,     // [4H][I]
          const float* __restrict__ Whh,     // [4H][H]
          const float* __restrict__ bih,
          const float* __restrict__ bhh,
          unsigned short* __restrict__ hH,   // [2][H/8][B][8] bf16 only
          int*   __restrict__ cnts,          // 16 counters, 64-int stride
          float* __restrict__ out)           // [B][H]
{
    __shared__ float red[2][2][3][2][16][17];     // [pa][mt][kh-1][u][bsub][17] ~26KB
    __shared__ unsigned short hstg[128][128];     // [chunk][b16*8] 32KB
    __shared__ float biaslds[4][16];              // [gate][j-within-block]
    __shared__ int hflag;                         // step-ready broadcast
    __shared__ int pairbar[4][2];                 // [kh][mt] stage handshake

    const int tid  = (int)threadIdx.x;
    const int l    = tid & 63;
    const int p    = __builtin_amdgcn_readfirstlane(tid >> 6);  // wave 0..7
    const int kh   = p & 3;                  // k-split 0..3
    const int mt   = p >> 2;                 // m-pair 0..1 (tiles mt*2+u)
    const int bsub = l & 15;
    const int q    = l >> 4;                 // quad

    const int jt = (int)blockIdx.x >> 2;     // 0..63  (16 channels each)
    const int bq = (int)blockIdx.x & 3;      // 0..3   (16 batch each)
    const int j0 = jt * 16;
    const int b0 = bq * 16;

    const int bofs = (b0 + bsub) * 8;        // u16 offset of my batch lane

    int*       prodc = cnts + (bq * 4 + (jt >> 4)) * 64;  // my quarter's counter
    const int* pollc = cnts + (bq * 4 + (l & 3)) * 64;    // poller: lane l&3's quarter

    // ---- weight A-fragments -> registers (persist across all t) ----
    bf16x8 whi[2][12], wlo[2][12];
#pragma unroll
    for (int u = 0; u < 2; ++u) {
        const int row = (l & 3) * HH + j0 + (mt * 2 + u) * 4 + ((l & 15) >> 2);
#pragma unroll
        for (int kt = 0; kt < 12; ++kt) {
            const int ktg = (kt < 4) ? (4 * kh + kt) : (16 + 8 * kh + (kt - 4));
            const float* src = (ktg < 16)
                ? (Wih + (size_t)row * II + ktg * 32 + q * 8)
                : (Whh + (size_t)row * HH + (ktg - 16) * 32 + q * 8);
            const float4 w0 = *(const float4*)src;
            const float4 w1 = *(const float4*)(src + 4);
            const float wf[8] = {w0.x, w0.y, w0.z, w0.w, w1.x, w1.y, w1.z, w1.w};
#pragma unroll
            for (int e = 0; e < 8; ++e) {
                unsigned hi, lo;
                split_bf16(wf[e], hi, lo);
                whi[u][kt][e] = (short)hi;
                wlo[u][kt][e] = (short)lo;
            }
        }
    }

    // ---- per-cell state; init h_0, ack, publish (R13 protocol) ----
    float c[2] = {0.f, 0.f}, lasth[2] = {0.f, 0.f};
    int len = 0;
    const size_t hchunk = (size_t)(2 * jt + mt) * 512;  // my output chunk row

    if (kh == 0) {
        len = lens[b0 + bsub];
#pragma unroll
        for (int u = 0; u < 2; ++u)
            store_wt_u16(hH + hchunk + bofs + 4 * u + q, 0);   // h_0 = 0, buffer 0
        asm volatile("s_waitcnt vmcnt(0)" ::: "memory");
        if (l == 0) atomic_add_rlx(prodc);               // -> 32 when all ready
    }

    // ---- bias table + flag/pairbar init before any poll ----
    if (tid < 64) {
        const int gi = tid >> 4, jj = tid & 15;
        biaslds[gi][jj] = bih[gi * HH + j0 + jj] + bhh[gi * HH + j0 + jj];
    }
    if (tid < 8)
        pairbar[tid & 3][tid >> 2] = 0;
    if (tid == 0)
        __hip_atomic_store(&hflag, 0, __ATOMIC_RELAXED, __HIP_MEMORY_SCOPE_WORKGROUP);
    __syncthreads();

    for (int t = 0; t < TT; ++t) {
        // ---- x-part (plain cached b128 loads; independent of h_t) ----
        f32x4 s0[2], s12[2];
#pragma unroll
        for (int u = 0; u < 2; ++u)
            s0[u] = s12[u] = (f32x4){0.f, 0.f, 0.f, 0.f};
        {
            const unsigned short* xh = xH + (size_t)t * XT_STRIDE;
            const unsigned short* xl = xL + (size_t)t * XT_STRIDE;
#pragma unroll
            for (int xi = 0; xi < 4; ++xi) {
                const int idx = ((4 * kh + xi) * 4 + q) * 512 + bofs;
                const bf16x8 ahi = *(const bf16x8*)(xh + idx);
                const bf16x8 alo = *(const bf16x8*)(xl + idx);
#pragma unroll
                for (int u = 0; u < 2; ++u) {
                    s0[u]  = MFMA(whi[u][xi], ahi, s0[u]);
                    s12[u] = MFMA(whi[u][xi], alo, s12[u]);
                    s12[u] = MFMA(wlo[u][xi], ahi, s12[u]);
                }
            }
        }

        // ---- step-ready: wave 7 polls 4 quarter counters, others spin LDS ----
        {
            const int need = 32 * (t + 1);
            if (p == 7) {
                while (load_rlx(pollc) < need)       // divergent: exits when all
                    __builtin_amdgcn_s_sleep(1);     // 4 quarters (l&3) pass
                if (l == 0)
                    __hip_atomic_store(&hflag, t + 1, __ATOMIC_RELAXED,
                                       __HIP_MEMORY_SCOPE_WORKGROUP);
            } else {
                while (__hip_atomic_load(&hflag, __ATOMIC_RELAXED,
                                         __HIP_MEMORY_SCOPE_WORKGROUP) < t + 1)
                    __builtin_amdgcn_s_sleep(1);
            }
            asm volatile("" ::: "memory");
        }

        // ---- h-part stage: wave loads its 16 chunks; pair handshake ----
        const unsigned short* hph = hH + (t & 1) * HBUF_STRIDE;
        {
            u32x4 fh[4];
#pragma unroll
            for (int r = 0; r < 4; ++r) {
                const int chunk = kh * 32 + mt * 16 + r * 4 + q;
                issue_coh(hph + chunk * 512 + bofs, fh[r]);
            }
            WAITSTG4(fh);
#pragma unroll
            for (int r = 0; r < 4; ++r) {
                const int chunk = kh * 32 + mt * 16 + r * 4 + q;
                *(u32x4*)&hstg[chunk][bsub * 8] = fh[r];
            }
        }
        // signal my half ready (release drains ds_writes), wait pair's half
        if (l == 0)
            __hip_atomic_store(&pairbar[kh][mt], t + 1, __ATOMIC_RELEASE,
                               __HIP_MEMORY_SCOPE_WORKGROUP);
        while (__hip_atomic_load(&pairbar[kh][mt ^ 1], __ATOMIC_ACQUIRE,
                                 __HIP_MEMORY_SCOPE_WORKGROUP) < t + 1)
            __builtin_amdgcn_s_sleep(1);
        asm volatile("" ::: "memory");

        // ---- h-part consume: 8 k-steps of my quarter from LDS (2 streams) ----
#pragma unroll
        for (int hi2 = 0; hi2 < 8; ++hi2) {
            const int chunk = kh * 32 + hi2 * 4 + q;
            const bf16x8 ahi = *(const bf16x8*)&hstg[chunk][bsub * 8];
#pragma unroll
            for (int u = 0; u < 2; ++u) {
                s0[u]  = MFMA(whi[u][4 + hi2], ahi, s0[u]);
                s12[u] = MFMA(wlo[u][4 + hi2], ahi, s12[u]);
            }
        }

        // ---- merge streams + single-phase cross-wave reduction ----
        f32x4 acc[2];
#pragma unroll
        for (int u = 0; u < 2; ++u) acc[u] = s0[u] + s12[u];
        const int pa = t & 1;

        if (kh != 0) {
#pragma unroll
            for (int u = 0; u < 2; ++u)
#pragma unroll
                for (int i = 0; i < 4; ++i)
                    red[pa][mt][kh - 1][u][bsub][4 * q + i] = acc[u][i];
        }
        __syncthreads();

        // ---- gate math (kh==0), h store, drain, publish — R17 exact ----
        if (kh == 0) {
            unsigned short* dsth = hH + ((t + 1) & 1) * HBUF_STRIDE + hchunk;
#pragma unroll
            for (int u = 0; u < 2; ++u) {
                const int jj = (mt * 2 + u) * 4 + q;
                const f32x4 r0 = *(const f32x4*)&red[pa][mt][0][u][bsub][4 * q];
                const f32x4 r1 = *(const f32x4*)&red[pa][mt][1][u][bsub][4 * q];
                const f32x4 r2 = *(const f32x4*)&red[pa][mt][2][u][bsub][4 * q];
                float g4[4];
#pragma unroll
                for (int i = 0; i < 4; ++i)
                    g4[i] = acc[u][i] + biaslds[i][jj] + r0[i] + r1[i] + r2[i];
                const float ig = fast_sigmoid(g4[0]);
                const float fg = fast_sigmoid(g4[1]);
                const float gg = fast_tanh(g4[2]);
                const float og = fast_sigmoid(g4[3]);
                c[u] = fg * c[u] + ig * gg;
                const float h = og * fast_tanh(c[u]);
                store_wt_u16(dsth + bofs + 4 * u + q, bf16_rne(h));
                if (t == len - 1) lasth[u] = h;
            }
            asm volatile("s_waitcnt vmcnt(0)" ::: "memory");  // h stores visible
            if (l == 0) atomic_add_rlx(prodc);                // publish h_{t+1}
        }
    }

    // ---- epilogue ----
    if (kh == 0) {
#pragma unroll
        for (int u = 0; u < 2; ++u) {
            const int jj = (mt * 2 + u) * 4 + q;
            out[(size_t)(b0 + bsub) * HH + j0 + jj] = lasth[u];
        }
    }
}

extern "C" void kernel_launch(void* const* d_in, const int* in_sizes, int n_in,
                              void* d_out, int out_size, void* d_ws, size_t ws_size,
                              hipStream_t stream)
{
    const float* seq  = (const float*)d_in[0];
    const int*   lens = (const int*)  d_in[1];
    const float* Wih  = (const float*)d_in[2];
    const float* Whh  = (const float*)d_in[3];
    const float* bih  = (const float*)d_in[4];
    const float* bhh  = (const float*)d_in[5];
    float* out = (float*)d_out;

    char* ws = (char*)d_ws;
    int*            cnts = (int*)           (ws + WS_CNT_OFF);
    unsigned short* hH   = (unsigned short*)(ws + WS_HPAKH_OFF);
    unsigned short* xH   = (unsigned short*)(ws + WS_XPAKH_OFF);
    unsigned short* xL   = (unsigned short*)(ws + WS_XPAKL_OFF);

    hipMemsetAsync(cnts, 0, 8192, stream);   // monotonic counters start at 0
    transpose_pack_x<<<dim3(TT), dim3(256), 0, stream>>>(seq, xH, xL);
    lstm_mfma<<<dim3(NBLK), dim3(NTHR), 0, stream>>>(xH, xL, lens, Wih, Whh, bih, bhh,
                                                     hH, cnts, out);
}

// Round 13
// 2135.449 us; speedup vs baseline: 1.2370x; 1.0808x over previous
//
#include <hip/hip_runtime.h>

// LSTM B=64 T=512 I=512 H=1024 — round 20.
// R19 (pair barrier): 2308us, kept. Remaining chain: publish segment has two
// untested inefficiencies: (a) 32 same-line counter RMWs serialize at one LLC
// slice; (b) each kh0 lane issues TWO u16 stores 8B apart => partial-mask
// line writes (RMW), 2x line ops. R20 refines publish only (no schedule
// change, no added hops — R14/15/16/18 lessons respected):
//  1) SUB-COUNTERS 16->64: counter per (bq, jt>>4, (jt>>2)&3) => 8 adds/line
//     (queue /4). need = 8*(t+1). Poller reads 16 lines via 16 lanes in one
//     parallel gather (R13 pattern, NOT R14's 64-line regather).
//  2) DWORD h PUBLISH: in-chunk channel order 4u+q -> 2q+u, so a lane's two
//     h values are adjacent => ONE full-dword coherent store per lane (64 vs
//     128 stores/wave, no sub-dword masks). Consumers compensate at WEIGHT
//     LOAD time: h-part A element e takes column perm(e)=4(e&1)+(e>>1) —
//     init-only cost. (k-slot reorder may wiggle absmax by FP sum order.)
// If neutral: publish segment exhausted -> declare structural roofline.

typedef short bf16x8 __attribute__((ext_vector_type(8)));
typedef float f32x4  __attribute__((ext_vector_type(4)));
typedef unsigned u32x4 __attribute__((ext_vector_type(4)));

#define BB 64
#define TT 512
#define II 512
#define HH 1024

#define NBLK 256
#define NTHR 512

// ws layout (bytes)
#define WS_CNT_OFF   0                       // 64 counters, 256B apart = 16 KB
#define WS_HPAKH_OFF 16384                   // u16 [2][HH/8][BB][8] = 256 KB
#define WS_XPAKH_OFF (1 << 20)               // u16 [TT][II/8][BB][8] = 32 MB
#define WS_XPAKL_OFF ((1 << 20) + (32u << 20))

#define HBUF_STRIDE 65536                    // u16 per h buffer
#define XT_STRIDE   32768                    // u16 per timestep of x

__device__ __forceinline__ int atomic_add_rlx(int* p) {
    return __hip_atomic_fetch_add(p, 1, __ATOMIC_RELAXED, __HIP_MEMORY_SCOPE_AGENT);
}
__device__ __forceinline__ int load_rlx(const int* p) {
    return __hip_atomic_load(p, __ATOMIC_RELAXED, __HIP_MEMORY_SCOPE_AGENT);
}
__device__ __forceinline__ void store_coh_u32(unsigned* p, unsigned v) {
    __hip_atomic_store(p, v, __ATOMIC_RELAXED, __HIP_MEMORY_SCOPE_AGENT);
}

__device__ __forceinline__ float fast_sigmoid(float x) {
    return 1.0f / (1.0f + __expf(-x));
}
__device__ __forceinline__ float fast_tanh(float x) {
    x = fminf(15.0f, fmaxf(-15.0f, x));
    const float e = __expf(2.0f * x);
    return (e - 1.0f) / (e + 1.0f);
}

// fp32 -> bf16 hi + bf16 lo-of-residual (RNE both)
__device__ __forceinline__ void split_bf16(float x, unsigned& hi, unsigned& lo)
{
    unsigned b = __float_as_uint(x);
    hi = (b + 0x7fffu + ((b >> 16) & 1u)) >> 16;
    float r = x - __uint_as_float(hi << 16);
    unsigned bl = __float_as_uint(r);
    lo = (bl + 0x7fffu + ((bl >> 16) & 1u)) >> 16;
}
// fp32 -> bf16 (RNE), hi only
__device__ __forceinline__ unsigned short bf16_rne(float x)
{
    unsigned b = __float_as_uint(x);
    return (unsigned short)((b + 0x7fffu + ((b >> 16) & 1u)) >> 16);
}

#define MFMA(A, B, C) __builtin_amdgcn_mfma_f32_16x16x32_bf16((A), (B), (C), 0, 0, 0)

// coherent 16B load, issued WITHOUT wait (MUST pair with WAITSTG4 below)
__device__ __forceinline__ void issue_coh(const unsigned short* p, u32x4& d)
{
    asm volatile("global_load_dwordx4 %0, %1, off sc0 sc1" : "=v"(d) : "v"(p));
}
// drain all VMEM; loaded values flow THROUGH the wait so uses can't be hoisted
#define WAITSTG4(FH)                                                          \
    asm volatile("s_waitcnt vmcnt(0)"                                         \
        : "+v"(FH[0]), "+v"(FH[1]), "+v"(FH[2]), "+v"(FH[3])                  \
        :: "memory")

// x -> split planes, layout [t][k>>3][b][k&7] u16 per plane
__global__ void __launch_bounds__(256)
transpose_pack_x(const float* __restrict__ x,
                 unsigned short* __restrict__ xH, unsigned short* __restrict__ xL)
{
    __shared__ float tile[64][65];
    const int t   = (int)blockIdx.x;
    const int tid = (int)threadIdx.x;
    const int li  = tid & 63;
    const int w4  = tid >> 6;

    for (int kc = 0; kc < II; kc += 64) {
#pragma unroll
        for (int r = 0; r < 16; ++r) {
            const int b = w4 * 16 + r;
            tile[b][li] = x[((size_t)b * TT + t) * II + kc + li];
        }
        __syncthreads();
#pragma unroll
        for (int half = 0; half < 2; ++half) {
            const int u  = tid + half * 256;      // u = k8*64 + b
            const int k8 = u >> 6, b = u & 63;
            unsigned short oh[8], ol[8];
#pragma unroll
            for (int e = 0; e < 8; ++e) {
                unsigned hi, lo;
                split_bf16(tile[b][k8 * 8 + e], hi, lo);
                oh[e] = (unsigned short)hi;
                ol[e] = (unsigned short)lo;
            }
            const size_t idx = (size_t)t * XT_STRIDE + ((kc >> 3) + k8) * 512 + b * 8;
            *(uint4*)(xH + idx) = *(const uint4*)oh;
            *(uint4*)(xL + idx) = *(const uint4*)ol;
        }
        __syncthreads();
    }
}

__global__ void __launch_bounds__(NTHR, 2)
lstm_mfma(const unsigned short* __restrict__ xH,
          const unsigned short* __restrict__ xL,
          const int*   __restrict__ lens,
          const float* __restrict__ Wih,     // [4H][I]
          const float* __restrict__ Whh,     // [4H][H]
          const float* __restrict__ bih,
          const float* __restrict__ bhh,
          unsigned short* __restrict__ hH,   // [2][H/8][B][8] bf16, chunk order 2q+u
          int*   __restrict__ cnts,          // 64 counters, 64-int stride
          float* __restrict__ out)           // [B][H]
{
    __shared__ float red[2][2][3][2][16][17];     // [pa][mt][kh-1][u][bsub][17] ~26KB
    __shared__ unsigned short hstg[128][128];     // [chunk][b16*8] 32KB
    __shared__ float biaslds[4][16];              // [gate][j-within-block]
    __shared__ int hflag;                         // step-ready broadcast
    __shared__ int pairbar[4][2];                 // [kh][mt] stage handshake

    const int tid  = (int)threadIdx.x;
    const int l    = tid & 63;
    const int p    = __builtin_amdgcn_readfirstlane(tid >> 6);  // wave 0..7
    const int kh   = p & 3;                  // k-split 0..3
    const int mt   = p >> 2;                 // m-pair 0..1 (tiles mt*2+u)
    const int bsub = l & 15;
    const int q    = l >> 4;                 // quad

    const int jt = (int)blockIdx.x >> 2;     // 0..63  (16 channels each)
    const int bq = (int)blockIdx.x & 3;      // 0..3   (16 batch each)
    const int j0 = jt * 16;
    const int b0 = bq * 16;

    const int bofs = (b0 + bsub) * 8;        // u16 offset of my batch lane

    // sub-counters: 8 producers each (4 jt-blocks x 2 kh0-waves)
    int*       prodc = cnts + (bq * 16 + (jt >> 4) * 4 + ((jt >> 2) & 3)) * 64;
    const int* pollc = cnts + (bq * 16 + (l & 3) * 4 + ((l >> 2) & 3)) * 64;

    // ---- weight A-fragments -> registers (persist across all t) ----
    // h-part k-slot e holds channel colbase + perm(e), perm(e)=4(e&1)+(e>>1)
    // (matches the 2q+u in-chunk store order of the h publish).
    bf16x8 whi[2][12], wlo[2][12];
#pragma unroll
    for (int u = 0; u < 2; ++u) {
        const int row = (l & 3) * HH + j0 + (mt * 2 + u) * 4 + ((l & 15) >> 2);
#pragma unroll
        for (int kt = 0; kt < 12; ++kt) {
            const int ktg = (kt < 4) ? (4 * kh + kt) : (16 + 8 * kh + (kt - 4));
            const float* src = (ktg < 16)
                ? (Wih + (size_t)row * II + ktg * 32 + q * 8)
                : (Whh + (size_t)row * HH + (ktg - 16) * 32 + q * 8);
            const float4 w0 = *(const float4*)src;
            const float4 w1 = *(const float4*)(src + 4);
            const float wraw[8] = {w0.x, w0.y, w0.z, w0.w, w1.x, w1.y, w1.z, w1.w};
#pragma unroll
            for (int e = 0; e < 8; ++e) {
                const int pe = (kt < 4) ? e : (4 * (e & 1) + (e >> 1));
                unsigned hi, lo;
                split_bf16(wraw[pe], hi, lo);
                whi[u][kt][e] = (short)hi;
                wlo[u][kt][e] = (short)lo;
            }
        }
    }

    // ---- per-cell state; init h_0, ack, publish ----
    float c[2] = {0.f, 0.f}, lasth[2] = {0.f, 0.f};
    int len = 0;
    const size_t hchunk = (size_t)(2 * jt + mt) * 512;  // my output chunk row

    if (kh == 0) {
        len = lens[b0 + bsub];
        store_coh_u32((unsigned*)(hH + hchunk + bofs + 2 * q), 0u);  // h_0 = 0
        asm volatile("s_waitcnt vmcnt(0)" ::: "memory");
        if (l == 0) atomic_add_rlx(prodc);               // -> 8 when all ready
    }

    // ---- bias table + flag/pairbar init before any poll ----
    if (tid < 64) {
        const int gi = tid >> 4, jj = tid & 15;
        biaslds[gi][jj] = bih[gi * HH + j0 + jj] + bhh[gi * HH + j0 + jj];
    }
    if (tid < 8)
        pairbar[tid & 3][tid >> 2] = 0;
    if (tid == 0)
        __hip_atomic_store(&hflag, 0, __ATOMIC_RELAXED, __HIP_MEMORY_SCOPE_WORKGROUP);
    __syncthreads();

    for (int t = 0; t < TT; ++t) {
        // ---- x-part (plain cached b128 loads; independent of h_t) ----
        f32x4 s0[2], s12[2];
#pragma unroll
        for (int u = 0; u < 2; ++u)
            s0[u] = s12[u] = (f32x4){0.f, 0.f, 0.f, 0.f};
        {
            const unsigned short* xh = xH + (size_t)t * XT_STRIDE;
            const unsigned short* xl = xL + (size_t)t * XT_STRIDE;
#pragma unroll
            for (int xi = 0; xi < 4; ++xi) {
                const int idx = ((4 * kh + xi) * 4 + q) * 512 + bofs;
                const bf16x8 ahi = *(const bf16x8*)(xh + idx);
                const bf16x8 alo = *(const bf16x8*)(xl + idx);
#pragma unroll
                for (int u = 0; u < 2; ++u) {
                    s0[u]  = MFMA(whi[u][xi], ahi, s0[u]);
                    s12[u] = MFMA(whi[u][xi], alo, s12[u]);
                    s12[u] = MFMA(wlo[u][xi], ahi, s12[u]);
                }
            }
        }

        // ---- step-ready: wave 7 polls 16 sub-counters (16 lanes), LDS flag ----
        {
            const int need = 8 * (t + 1);
            if (p == 7) {
                while (load_rlx(pollc) < need)       // divergent: exits when all
                    __builtin_amdgcn_s_sleep(1);     // 16 sub-counters pass
                if (l == 0)
                    __hip_atomic_store(&hflag, t + 1, __ATOMIC_RELAXED,
                                       __HIP_MEMORY_SCOPE_WORKGROUP);
            } else {
                while (__hip_atomic_load(&hflag, __ATOMIC_RELAXED,
                                         __HIP_MEMORY_SCOPE_WORKGROUP) < t + 1)
                    __builtin_amdgcn_s_sleep(1);
            }
            asm volatile("" ::: "memory");
        }

        // ---- h-part stage: wave loads its 16 chunks; pair handshake ----
        const unsigned short* hph = hH + (t & 1) * HBUF_STRIDE;
        {
            u32x4 fh[4];
#pragma unroll
            for (int r = 0; r < 4; ++r) {
                const int chunk = kh * 32 + mt * 16 + r * 4 + q;
                issue_coh(hph + chunk * 512 + bofs, fh[r]);
            }
            WAITSTG4(fh);
#pragma unroll
            for (int r = 0; r < 4; ++r) {
                const int chunk = kh * 32 + mt * 16 + r * 4 + q;
                *(u32x4*)&hstg[chunk][bsub * 8] = fh[r];
            }
        }
        // signal my half ready (release drains ds_writes), wait pair's half
        if (l == 0)
            __hip_atomic_store(&pairbar[kh][mt], t + 1, __ATOMIC_RELEASE,
                               __HIP_MEMORY_SCOPE_WORKGROUP);
        while (__hip_atomic_load(&pairbar[kh][mt ^ 1], __ATOMIC_ACQUIRE,
                                 __HIP_MEMORY_SCOPE_WORKGROUP) < t + 1)
            __builtin_amdgcn_s_sleep(1);
        asm volatile("" ::: "memory");

        // ---- h-part consume: 8 k-steps of my quarter from LDS (2 streams) ----
#pragma unroll
        for (int hi2 = 0; hi2 < 8; ++hi2) {
            const int chunk = kh * 32 + hi2 * 4 + q;
            const bf16x8 ahi = *(const bf16x8*)&hstg[chunk][bsub * 8];
#pragma unroll
            for (int u = 0; u < 2; ++u) {
                s0[u]  = MFMA(whi[u][4 + hi2], ahi, s0[u]);
                s12[u] = MFMA(wlo[u][4 + hi2], ahi, s12[u]);
            }
        }

        // ---- merge streams + single-phase cross-wave reduction ----
        f32x4 acc[2];
#pragma unroll
        for (int u = 0; u < 2; ++u) acc[u] = s0[u] + s12[u];
        const int pa = t & 1;

        if (kh != 0) {
#pragma unroll
            for (int u = 0; u < 2; ++u)
#pragma unroll
                for (int i = 0; i < 4; ++i)
                    red[pa][mt][kh - 1][u][bsub][4 * q + i] = acc[u][i];
        }
        __syncthreads();

        // ---- gate math (kh==0), dword h store, drain, publish ----
        if (kh == 0) {
            unsigned short* dsth = hH + ((t + 1) & 1) * HBUF_STRIDE + hchunk;
            unsigned short hpk[2];
#pragma unroll
            for (int u = 0; u < 2; ++u) {
                const int jj = (mt * 2 + u) * 4 + q;
                const f32x4 r0 = *(const f32x4*)&red[pa][mt][0][u][bsub][4 * q];
                const f32x4 r1 = *(const f32x4*)&red[pa][mt][1][u][bsub][4 * q];
                const f32x4 r2 = *(const f32x4*)&red[pa][mt][2][u][bsub][4 * q];
                float g4[4];
#pragma unroll
                for (int i = 0; i < 4; ++i)
                    g4[i] = acc[u][i] + biaslds[i][jj] + r0[i] + r1[i] + r2[i];
                const float ig = fast_sigmoid(g4[0]);
                const float fg = fast_sigmoid(g4[1]);
                const float gg = fast_tanh(g4[2]);
                const float og = fast_sigmoid(g4[3]);
                c[u] = fg * c[u] + ig * gg;
                const float h = og * fast_tanh(c[u]);
                hpk[u] = bf16_rne(h);
                if (t == len - 1) lasth[u] = h;
            }
            // one full-dword coherent store: channels (2q+0, 2q+1) adjacent
            store_coh_u32((unsigned*)(dsth + bofs + 2 * q),
                          (unsigned)hpk[0] | ((unsigned)hpk[1] << 16));
            asm volatile("s_waitcnt vmcnt(0)" ::: "memory");  // h stores visible
            if (l == 0) atomic_add_rlx(prodc);                // publish h_{t+1}
        }
    }

    // ---- epilogue ----
    if (kh == 0) {
#pragma unroll
        for (int u = 0; u < 2; ++u) {
            const int jj = (mt * 2 + u) * 4 + q;
            out[(size_t)(b0 + bsub) * HH + j0 + jj] = lasth[u];
        }
    }
}

extern "C" void kernel_launch(void* const* d_in, const int* in_sizes, int n_in,
                              void* d_out, int out_size, void* d_ws, size_t ws_size,
                              hipStream_t stream)
{
    const float* seq  = (const float*)d_in[0];
    const int*   lens = (const int*)  d_in[1];
    const float* Wih  = (const float*)d_in[2];
    const float* Whh  = (const float*)d_in[3];
    const float* bih  = (const float*)d_in[4];
    const float* bhh  = (const float*)d_in[5];
    float* out = (float*)d_out;

    char* ws = (char*)d_ws;
    int*            cnts = (int*)           (ws + WS_CNT_OFF);
    unsigned short* hH   = (unsigned short*)(ws + WS_HPAKH_OFF);
    unsigned short* xH   = (unsigned short*)(ws + WS_XPAKH_OFF);
    unsigned short* xL   = (unsigned short*)(ws + WS_XPAKL_OFF);

    hipMemsetAsync(cnts, 0, 16384, stream);  // 64 monotonic counters start at 0
    transpose_pack_x<<<dim3(TT), dim3(256), 0, stream>>>(seq, xH, xL);
    lstm_mfma<<<dim3(NBLK), dim3(NTHR), 0, stream>>>(xH, xL, lens, Wih, Whh, bih, bhh,
                                                     hH, cnts, out);
}